// Round 2
// baseline (718.089 us; speedup 1.0000x reference)
//
#include <hip/hip_runtime.h>
#include <math.h>

// Keep all float arithmetic un-contracted (separate mul/add like the numpy/jax
// f32 reference) so discrete decisions (argmax, top-k order, iou>thr) match.
#pragma clang fp contract(off)

// ---------------- problem constants ----------------
#define BB      8
#define AA      9
#define NCLS    80
#define NTOT    72000      // 57600 + 14400 boxes per image
#define N0BASE  57600
#define PRE     1000
#define POST    300
#define CAP     4096       // candidate cap per image (expected ~1100)
#define NBINS   65536
#define BCLIP   4.135166556742356f   // log(1000/16)

__device__ __constant__ float c_sizes[9] = {16.f,32.f,64.f,20.f,40.f,80.f,24.f,48.f,96.f};

__device__ inline unsigned fkey(float s) {
    unsigned u = __float_as_uint(s);
    return (u & 0x80000000u) ? ~u : (u | 0x80000000u);
}

// ---------------- kernel 1: decode + score max/argmax + histogram ----------------
// thread handles 4 consecutive hw cells of one (b, a); lanes are hw-contiguous
// so every channel read is a coalesced 1KB wave transaction.
__global__ __launch_bounds__(256) void k_decode(
    const float* __restrict__ data0, const float* __restrict__ data1,
    float* __restrict__ boxes, float* __restrict__ scores, float* __restrict__ cls,
    unsigned* __restrict__ hist)
{
    int t = blockIdx.x * 256 + threadIdx.x;
    int b = blockIdx.y;
    if (t >= 18000) return;

    const float* dbase; int a, q, HW, W, nbase; float stride;
    if (t < 14400) { a = t / 1600; q = t - a * 1600; HW = 6400; W = 80; stride = 8.f;  nbase = 0;      dbase = data0; }
    else { int t2 = t - 14400; a = t2 / 400; q = t2 - a * 400; HW = 1600; W = 40; stride = 16.f; nbase = N0BASE; dbase = data1; }

    const float* p = dbase + (size_t)(b * 756 + a * 84) * HW + q * 4;

    float dxv[4], dyv[4], dwv[4], dhv[4], bestv[4], sv[4];
    int biv[4] = {0,0,0,0};
    *(float4*)dxv = *(const float4*)(p);
    *(float4*)dyv = *(const float4*)(p + HW);
    *(float4*)dwv = *(const float4*)(p + 2 * (size_t)HW);
    *(float4*)dhv = *(const float4*)(p + 3 * (size_t)HW);

    const float* sp = p + 4 * (size_t)HW;
    *(float4*)bestv = *(const float4*)(sp);
    for (int j = 1; j < NCLS; j++) {
        sp += HW;
        *(float4*)sv = *(const float4*)(sp);
        #pragma unroll
        for (int k = 0; k < 4; k++)
            if (sv[k] > bestv[k]) { bestv[k] = sv[k]; biv[k] = j; }
    }

    float sz = c_sizes[a];
    int hw0 = q * 4;
    int h = hw0 / W;
    int w0 = hw0 - h * W;
    float cy = (h + 0.5f) * stride;

    #pragma unroll
    for (int k = 0; k < 4; k++) {
        float cx  = (w0 + k + 0.5f) * stride;
        float pcx = dxv[k] * sz + cx;
        float pcy = dyv[k] * sz + cy;
        float pw  = expf(fminf(dwv[k], BCLIP)) * sz;
        float ph  = expf(fminf(dhv[k], BCLIP)) * sz;
        float x1 = fminf(fmaxf(pcx - 0.5f * pw, 0.f), 640.f);
        float y1 = fminf(fmaxf(pcy - 0.5f * ph, 0.f), 640.f);
        float x2 = fminf(fmaxf(pcx + 0.5f * pw, 0.f), 640.f);
        float y2 = fminf(fmaxf(pcy + 0.5f * ph, 0.f), 640.f);

        int n = nbase + (hw0 + k) * AA + a;
        size_t o = (size_t)b * NTOT + n;
        ((float4*)boxes)[o] = make_float4(x1, y1, x2, y2);
        scores[o] = bestv[k];
        cls[o] = (float)biv[k];
        atomicAdd(&hist[(size_t)b * NBINS + (fkey(bestv[k]) >> 16)], 1u);
    }
}

// ---------------- kernel 2: find per-image 16-bit threshold bucket ----------------
__global__ __launch_bounds__(256) void k_thresh(const unsigned* __restrict__ hist,
                                                unsigned* __restrict__ T)
{
    __shared__ unsigned csum[256];
    int b = blockIdx.x, tid = threadIdx.x;
    const unsigned* hb = hist + (size_t)b * NBINS;
    unsigned s = 0;
    for (int i = 0; i < 256; i++) s += hb[tid * 256 + i];
    csum[tid] = s;
    __syncthreads();
    if (tid == 0) {
        unsigned cum = 0; int C = 0;
        for (int c = 255; c >= 0; c--) {
            if (cum + csum[c] >= (unsigned)PRE) { C = c; break; }
            cum += csum[c];
        }
        unsigned Tv = (unsigned)(C * 256);
        for (int bin = C * 256 + 255; bin >= C * 256; bin--) {
            cum += hb[bin];
            if (cum >= (unsigned)PRE) { Tv = (unsigned)bin; break; }
        }
        T[b] = Tv;
    }
}

// ---------------- kernel 3: compact candidates >= threshold bucket ----------------
__global__ __launch_bounds__(256) void k_compact(const float* __restrict__ scores,
                                                 const unsigned* __restrict__ T,
                                                 unsigned* __restrict__ cnt,
                                                 unsigned long long* __restrict__ cand)
{
    int n = blockIdx.x * 256 + threadIdx.x;
    int b = blockIdx.y;
    if (n >= NTOT) return;
    unsigned u = fkey(scores[(size_t)b * NTOT + n]);
    if ((u >> 16) >= T[b]) {
        unsigned pos = atomicAdd(&cnt[b], 1u);
        if (pos < CAP)
            cand[(size_t)b * CAP + pos] = ((unsigned long long)u << 32) | (unsigned)(~(unsigned)n);
    }
}

// ---------------- kernel 4: per-image bitonic sort + gather top-1000 dense ----------------
__global__ __launch_bounds__(1024) void k_sort(
    const unsigned long long* __restrict__ cand, const unsigned* __restrict__ cnt,
    const float* __restrict__ boxes, const float* __restrict__ scores, const float* __restrict__ cls,
    float* __restrict__ sboxes, float* __restrict__ sscores, float* __restrict__ scls)
{
    __shared__ unsigned long long keys[CAP];
    int b = blockIdx.x, tid = threadIdx.x;
    int c = min((int)cnt[b], CAP);
    for (int i = tid; i < CAP; i += 1024)
        keys[i] = (i < c) ? cand[(size_t)b * CAP + i] : 0ULL;

    for (int k2 = 2; k2 <= CAP; k2 <<= 1)
        for (int j = k2 >> 1; j > 0; j >>= 1) {
            __syncthreads();
            for (int i = tid; i < CAP; i += 1024) {
                int l = i ^ j;
                if (l > i) {
                    unsigned long long x = keys[i], y = keys[l];
                    bool up = ((i & k2) == 0);
                    if ((x > y) == up) { keys[i] = y; keys[l] = x; }
                }
            }
        }
    __syncthreads();

    if (tid < PRE) {
        unsigned long long key = keys[CAP - 1 - tid];       // descending
        unsigned n = ~(unsigned)(key & 0xFFFFFFFFu);
        size_t src = (size_t)b * NTOT + n;
        ((float4*)sboxes)[b * 1024 + tid] = ((const float4*)boxes)[src];
        sscores[b * 1024 + tid] = scores[src];
        scls[b * 1024 + tid] = cls[src];
    }
}

// ---------------- kernel 5: suppression bitmask (1000 x 1000) ----------------
// grid (word w = 0..15, image b); lane = row r -> bx[j] reads are wave-uniform broadcasts.
__global__ __launch_bounds__(1024) void k_mask(const float* __restrict__ sboxes,
                                               const float* __restrict__ sscores,
                                               unsigned long long* __restrict__ mask)
{
    __shared__ float4 bx[PRE];
    __shared__ float  sl[PRE];
    int b = blockIdx.y, w = blockIdx.x, tid = threadIdx.x;
    for (int i = tid; i < PRE; i += 1024) {
        bx[i] = ((const float4*)sboxes)[b * 1024 + i];
        sl[i] = sscores[b * 1024 + i];
    }
    __syncthreads();
    if (tid >= PRE) return;
    int r = tid;
    float4 br = bx[r];
    float sr = sl[r];
    float arear = (br.z - br.x) * (br.w - br.y);
    unsigned long long bits = 0;
    int jend = min(64, PRE - w * 64);
    for (int jj = 0; jj < jend; jj++) {
        int j = w * 64 + jj;
        float4 bj = bx[j];
        float ix1 = fmaxf(br.x, bj.x), iy1 = fmaxf(br.y, bj.y);
        float ix2 = fminf(br.z, bj.z), iy2 = fminf(br.w, bj.w);
        float iw = fmaxf(ix2 - ix1, 0.f), ih = fmaxf(iy2 - iy1, 0.f);
        float inter = iw * ih;
        float areaj = (bj.z - bj.x) * (bj.w - bj.y);
        float iou = inter / (arear + areaj - inter + 1e-9f);
        if (j > r && iou > 0.5f && sr > sl[j]) bits |= 1ull << jj;
    }
    mask[((size_t)(b * 1024) + r) * 16 + w] = bits;
}

// ---------------- kernel 6: sequential greedy pass + output ----------------
// one wave per image; lanes 0..15 hold the 16 remv words; mask rows prefetched.
__global__ __launch_bounds__(64) void k_nms(const unsigned long long* __restrict__ mask,
                                            const float* __restrict__ sboxes,
                                            const float* __restrict__ sscores,
                                            const float* __restrict__ scls,
                                            float* __restrict__ out)
{
    int b = blockIdx.x, lane = threadIdx.x;

    unsigned long long validw = 0;
    for (int w = 0; w < 16; w++) {
        int r = w * 64 + lane;
        bool v = false;
        if (r < PRE) {
            float sc = sscores[b * 1024 + r];
            float4 bb = ((const float4*)sboxes)[b * 1024 + r];
            v = (sc >= 0.05f) && (bb.x < bb.z) && (bb.y < bb.w);
        }
        unsigned long long bal = __ballot(v);
        if (lane == w) validw = bal;
    }

    const unsigned long long* mrow = mask + (size_t)b * 1024 * 16;
    unsigned long long remv = 0;
    unsigned long long m = (lane < 16) ? mrow[lane] : 0ULL;
    for (int i = 0; i < PRE; i++) {
        unsigned long long mn = (lane < 16 && i + 1 < PRE) ? mrow[(size_t)(i + 1) * 16 + lane] : 0ULL;
        unsigned long long kw = validw & ~remv;
        unsigned long long kwb = __shfl(kw, i >> 6);
        if ((kwb >> (i & 63)) & 1ULL) remv |= m;
        m = mn;
    }

    __shared__ unsigned long long kws[16];
    __shared__ int pfx[17];
    if (lane < 16) kws[lane] = validw & ~remv;
    __syncthreads();
    if (lane == 0) {
        int s = 0;
        for (int w = 0; w < 16; w++) { pfx[w] = s; s += __popcll(kws[w]); }
        pfx[16] = s;
    }
    __syncthreads();
    int nk = pfx[16];

    float* ob = out;                       // [8][300][4]
    float* os = out + BB * POST * 4;       // [8][300]
    float* oc = os + BB * POST;            // [8][300]

    for (int r = lane; r < PRE; r += 64) {
        int w = r >> 6;
        unsigned long long kw = kws[w];
        if ((kw >> (r & 63)) & 1ULL) {
            int rank = pfx[w] + __popcll(kw & ((1ULL << (r & 63)) - 1ULL));
            if (rank < POST) {
                ((float4*)ob)[b * POST + rank] = ((const float4*)sboxes)[b * 1024 + r];
                os[b * POST + rank] = sscores[b * 1024 + r];
                oc[b * POST + rank] = scls[b * 1024 + r];
            }
        }
    }
    for (int p = nk + lane; p < POST; p += 64) {
        ((float4*)ob)[b * POST + p] = make_float4(0.f, 0.f, 0.f, 0.f);
        os[b * POST + p] = 0.f;
        oc[b * POST + p] = 0.f;
    }
}

// ---------------- launch ----------------
extern "C" void kernel_launch(void* const* d_in, const int* in_sizes, int n_in,
                              void* d_out, int out_size, void* d_ws, size_t ws_size,
                              hipStream_t stream)
{
    const float* data0 = (const float*)d_in[0];
    const float* data1 = (const float*)d_in[2];
    for (int i = 0; i < n_in; i++) {
        if (in_sizes[i] == 8 * 756 * 6400) data0 = (const float*)d_in[i];
        else if (in_sizes[i] == 8 * 756 * 1600) data1 = (const float*)d_in[i];
    }

    char* ws = (char*)d_ws;
    size_t off = 0;
    auto alloc = [&](size_t bytes) -> char* {
        char* p = ws + off;
        off = (off + bytes + 255) & ~(size_t)255;
        return p;
    };

    float* boxes   = (float*)alloc((size_t)BB * NTOT * 4 * 4);
    float* scores  = (float*)alloc((size_t)BB * NTOT * 4);
    float* cls     = (float*)alloc((size_t)BB * NTOT * 4);
    unsigned* hist = (unsigned*)alloc((size_t)BB * NBINS * 4);
    unsigned* cnt  = (unsigned*)alloc(BB * 4);          // directly after hist (256-aligned)
    unsigned* T    = (unsigned*)alloc(BB * 4);
    unsigned long long* cand = (unsigned long long*)alloc((size_t)BB * CAP * 8);
    float* sboxes  = (float*)alloc((size_t)BB * 1024 * 4 * 4);
    float* sscores = (float*)alloc((size_t)BB * 1024 * 4);
    float* scls    = (float*)alloc((size_t)BB * 1024 * 4);
    unsigned long long* mask = (unsigned long long*)alloc((size_t)BB * 1024 * 16 * 8);

    // zero hist + cnt (contiguous: hist is BB*NBINS*4 = 2,097,152 B, 256-multiple; cnt follows)
    (void)hipMemsetAsync(hist, 0, (size_t)BB * NBINS * 4 + 256, stream);

    dim3 g1((18000 + 255) / 256, BB);
    k_decode<<<g1, 256, 0, stream>>>(data0, data1, boxes, scores, cls, hist);

    k_thresh<<<BB, 256, 0, stream>>>(hist, T);

    dim3 g3((NTOT + 255) / 256, BB);
    k_compact<<<g3, 256, 0, stream>>>(scores, T, cnt, cand);

    k_sort<<<BB, 1024, 0, stream>>>(cand, cnt, boxes, scores, cls, sboxes, sscores, scls);

    dim3 g5(16, BB);
    k_mask<<<g5, 1024, 0, stream>>>(sboxes, sscores, mask);

    k_nms<<<BB, 64, 0, stream>>>(mask, sboxes, sscores, scls, (float*)d_out);
}

// Round 3
// 601.810 us; speedup vs baseline: 1.1932x; 1.1932x over previous
//
#include <hip/hip_runtime.h>
#include <math.h>

// Keep all float arithmetic un-contracted (separate mul/add like the numpy/jax
// f32 reference) so discrete decisions (argmax, top-k order, iou>thr) match.
#pragma clang fp contract(off)

// ---------------- problem constants ----------------
#define BB      8
#define AA      9
#define NCLS    80
#define NTOT    72000      // 57600 + 14400 boxes per image
#define PRE     1000
#define POST    300
#define CAP     4096       // candidate cap per image (expected ~1100-3000)
#define NBINS   65536
#define BCLIP   4.135166556742356f   // log(1000/16)

__device__ __constant__ float c_sizes[9] = {16.f,32.f,64.f,20.f,40.f,80.f,24.f,48.f,96.f};

__device__ inline unsigned fkey(float s) {
    unsigned u = __float_as_uint(s);
    return (u & 0x80000000u) ? ~u : (u | 0x80000000u);
}

// ---------------- kernel 1: decode + score max/argmax + histogram ----------------
// Internal storage layout: m = MBASE + a*HW + hw  (contiguous per (a,row)) so all
// stores are coalesced float4. Reference index n = hw*9 + a is recomputed later.
// Score loop loads 8 channels per batch -> 8 wave-loads in flight (latency hiding).
template<int HW, int W, int STRIDE, int MBASE>
__global__ __launch_bounds__(256) void k_decode(
    const float* __restrict__ data,
    float* __restrict__ boxes, float* __restrict__ scores, float* __restrict__ cls,
    unsigned* __restrict__ hist)
{
    constexpr int Q = HW / 4;
    int t = blockIdx.x * 256 + threadIdx.x;
    int b = blockIdx.y;
    if (t >= AA * Q) return;
    int a = t / Q;
    int q = t - a * Q;

    const float* p = data + (size_t)(b * 756 + a * 84) * HW + q * 4;

    float dxv[4], dyv[4], dwv[4], dhv[4];
    *(float4*)dxv = *(const float4*)(p);
    *(float4*)dyv = *(const float4*)(p + HW);
    *(float4*)dwv = *(const float4*)(p + 2 * (size_t)HW);
    *(float4*)dhv = *(const float4*)(p + 3 * (size_t)HW);

    const float* sp = p + 4 * (size_t)HW;
    float bestv[4] = {-1e30f, -1e30f, -1e30f, -1e30f};
    int biv[4] = {0, 0, 0, 0};

    for (int j0 = 0; j0 < NCLS; j0 += 8) {
        float4 s[8];
        #pragma unroll
        for (int u = 0; u < 8; u++)
            s[u] = *(const float4*)(sp + (size_t)(j0 + u) * HW);
        #pragma unroll
        for (int u = 0; u < 8; u++) {
            float sv[4];
            *(float4*)sv = s[u];
            #pragma unroll
            for (int k = 0; k < 4; k++)
                if (sv[k] > bestv[k]) { bestv[k] = sv[k]; biv[k] = j0 + u; }
        }
    }

    float sz = c_sizes[a];
    int hw0 = q * 4;
    int h = hw0 / W;
    int w0 = hw0 - h * W;
    float cy = (h + 0.5f) * (float)STRIDE;

    int m0 = MBASE + a * HW + hw0;
    size_t ob = (size_t)b * NTOT + m0;

    float clsv[4];
    #pragma unroll
    for (int k = 0; k < 4; k++) {
        float cx  = (w0 + k + 0.5f) * (float)STRIDE;
        float pcx = dxv[k] * sz + cx;
        float pcy = dyv[k] * sz + cy;
        float pw  = expf(fminf(dwv[k], BCLIP)) * sz;
        float ph  = expf(fminf(dhv[k], BCLIP)) * sz;
        float x1 = fminf(fmaxf(pcx - 0.5f * pw, 0.f), 640.f);
        float y1 = fminf(fmaxf(pcy - 0.5f * ph, 0.f), 640.f);
        float x2 = fminf(fmaxf(pcx + 0.5f * pw, 0.f), 640.f);
        float y2 = fminf(fmaxf(pcy + 0.5f * ph, 0.f), 640.f);
        ((float4*)boxes)[ob + k] = make_float4(x1, y1, x2, y2);
        clsv[k] = (float)biv[k];
        atomicAdd(&hist[(size_t)b * NBINS + (fkey(bestv[k]) >> 16)], 1u);
    }
    *(float4*)(scores + ob) = *(float4*)bestv;
    *(float4*)(cls + ob)    = *(float4*)clsv;
}

// ---------------- kernel 2: per-image 16-bit threshold bucket (LDS suffix scans) ----------------
__global__ __launch_bounds__(256) void k_thresh(const unsigned* __restrict__ hist,
                                                unsigned* __restrict__ T)
{
    __shared__ unsigned S[256];
    __shared__ int Csh;
    __shared__ unsigned cumAbove;
    int b = blockIdx.x, tid = threadIdx.x;
    const unsigned* hb = hist + (size_t)b * NBINS;
    const uint4* hb4 = (const uint4*)hb;

    unsigned s = 0;
    for (int i = 0; i < 64; i++) {
        uint4 v = hb4[tid * 64 + i];
        s += v.x + v.y + v.z + v.w;
    }
    S[tid] = s;
    __syncthreads();
    for (int off = 1; off < 256; off <<= 1) {   // suffix sum: S[c] = sum_{c'>=c}
        unsigned v = S[tid] + ((tid + off < 256) ? S[tid + off] : 0u);
        __syncthreads();
        S[tid] = v;
        __syncthreads();
    }
    if (S[tid] >= (unsigned)PRE && (tid == 255 || S[tid + 1] < (unsigned)PRE)) {
        Csh = tid;
        cumAbove = (tid == 255) ? 0u : S[tid + 1];
    }
    __syncthreads();
    int C = Csh; unsigned ca = cumAbove;
    unsigned f = hb[C * 256 + tid];
    __syncthreads();
    S[tid] = f;
    __syncthreads();
    for (int off = 1; off < 256; off <<= 1) {
        unsigned v = S[tid] + ((tid + off < 256) ? S[tid + off] : 0u);
        __syncthreads();
        S[tid] = v;
        __syncthreads();
    }
    if (ca + S[tid] >= (unsigned)PRE && (tid == 255 || ca + S[tid + 1] < (unsigned)PRE))
        T[b] = (unsigned)(C * 256 + tid);
}

// ---------------- kernel 3: compact candidates >= threshold bucket ----------------
__global__ __launch_bounds__(256) void k_compact(const float* __restrict__ scores,
                                                 const unsigned* __restrict__ T,
                                                 unsigned* __restrict__ cnt,
                                                 unsigned long long* __restrict__ cand)
{
    int m4 = blockIdx.x * 256 + threadIdx.x;
    int b = blockIdx.y;
    if (m4 >= NTOT / 4) return;
    float sv[4];
    *(float4*)sv = ((const float4*)(scores + (size_t)b * NTOT))[m4];
    unsigned Tb = T[b];
    #pragma unroll
    for (int k = 0; k < 4; k++) {
        unsigned u = fkey(sv[k]);
        if ((u >> 16) >= Tb) {
            int m = m4 * 4 + k;
            int n;
            if (m < 57600) { int a = m / 6400; int hw = m - a * 6400; n = hw * 9 + a; }
            else { int mm = m - 57600; int a = mm / 1600; int hw = mm - a * 1600; n = 57600 + hw * 9 + a; }
            unsigned pos = atomicAdd(&cnt[b], 1u);
            if (pos < CAP)
                cand[(size_t)b * CAP + pos] = ((unsigned long long)u << 32) | (unsigned)(~(unsigned)n);
        }
    }
}

// ---------------- kernel 4: per-image bitonic sort + gather top-1000 dense ----------------
__global__ __launch_bounds__(1024) void k_sort(
    const unsigned long long* __restrict__ cand, const unsigned* __restrict__ cnt,
    const float* __restrict__ boxes, const float* __restrict__ scores, const float* __restrict__ cls,
    float* __restrict__ sboxes, float* __restrict__ sscores, float* __restrict__ scls)
{
    __shared__ unsigned long long keys[CAP];
    int b = blockIdx.x, tid = threadIdx.x;
    int c = min((int)cnt[b], CAP);
    for (int i = tid; i < CAP; i += 1024)
        keys[i] = (i < c) ? cand[(size_t)b * CAP + i] : 0ULL;

    for (int k2 = 2; k2 <= CAP; k2 <<= 1)
        for (int j = k2 >> 1; j > 0; j >>= 1) {
            __syncthreads();
            for (int i = tid; i < CAP; i += 1024) {
                int l = i ^ j;
                if (l > i) {
                    unsigned long long x = keys[i], y = keys[l];
                    bool up = ((i & k2) == 0);
                    if ((x > y) == up) { keys[i] = y; keys[l] = x; }
                }
            }
        }
    __syncthreads();

    if (tid < PRE) {
        unsigned long long key = keys[CAP - 1 - tid];       // descending
        int n = (int)~(unsigned)(key & 0xFFFFFFFFu);
        int m;
        if (n < 57600) { int hw = n / 9; int a = n - hw * 9; m = a * 6400 + hw; }
        else { int n2 = n - 57600; int hw = n2 / 9; int a = n2 - hw * 9; m = 57600 + a * 1600 + hw; }
        size_t src = (size_t)b * NTOT + m;
        ((float4*)sboxes)[b * 1024 + tid] = ((const float4*)boxes)[src];
        sscores[b * 1024 + tid] = scores[src];
        scls[b * 1024 + tid] = cls[src];
    }
}

// ---------------- kernel 5: suppression bitmask (1000 x 1000) ----------------
// grid (word w, image b); lane = row r. Only the 64 j-boxes of word w go to LDS.
// Lower-triangle (all j <= r) stores 0 immediately.
__global__ __launch_bounds__(1024) void k_mask(const float* __restrict__ sboxes,
                                               const float* __restrict__ sscores,
                                               unsigned long long* __restrict__ mask)
{
    __shared__ float4 bx[64];
    __shared__ float  sl[64];
    int b = blockIdx.y, w = blockIdx.x, tid = threadIdx.x;
    if (tid < 64) {
        int j = w * 64 + tid;
        bx[tid] = ((const float4*)sboxes)[b * 1024 + j];   // rows >=1000 garbage, never used
        sl[tid] = sscores[b * 1024 + j];
    }
    __syncthreads();
    int r = tid;
    unsigned long long* dst = &mask[((size_t)(b * 1024) + r) * 16 + w];
    if (r >= PRE || w * 64 + 63 <= r) { *dst = 0ULL; return; }

    float4 br = ((const float4*)sboxes)[b * 1024 + r];
    float sr = sscores[b * 1024 + r];
    float arear = (br.z - br.x) * (br.w - br.y);
    unsigned long long bits = 0;
    int jend = min(64, PRE - w * 64);
    for (int jj = 0; jj < jend; jj++) {
        int j = w * 64 + jj;
        float4 bj = bx[jj];
        float ix1 = fmaxf(br.x, bj.x), iy1 = fmaxf(br.y, bj.y);
        float ix2 = fminf(br.z, bj.z), iy2 = fminf(br.w, bj.w);
        float iw = fmaxf(ix2 - ix1, 0.f), ih = fmaxf(iy2 - iy1, 0.f);
        float inter = iw * ih;
        float areaj = (bj.z - bj.x) * (bj.w - bj.y);
        float iou = inter / (arear + areaj - inter + 1e-9f);
        if (j > r && iou > 0.5f && sr > sl[jj]) bits |= 1ull << jj;
    }
    *dst = bits;
}

// ---------------- kernel 6: chunked greedy NMS + output (one wave per image) ----
// Per 64-box chunk: all rows loaded in parallel (one latency per chunk), serial
// intra-word resolution via shfl chain, cross-word suppression via butterfly OR.
__global__ __launch_bounds__(64) void k_nms(const unsigned long long* __restrict__ mask,
                                            const float* __restrict__ sboxes,
                                            const float* __restrict__ sscores,
                                            const float* __restrict__ scls,
                                            float* __restrict__ out)
{
    int b = blockIdx.x, lane = threadIdx.x;
    const unsigned long long* mrow = mask + (size_t)b * 1024 * 16;

    unsigned long long validw = 0;
    for (int w = 0; w < 16; w++) {
        int r = w * 64 + lane;
        bool v = false;
        if (r < PRE) {
            float sc = sscores[b * 1024 + r];
            float4 bbx = ((const float4*)sboxes)[b * 1024 + r];
            v = (sc >= 0.05f) && (bbx.x < bbx.z) && (bbx.y < bbx.w);
        }
        unsigned long long bal = __ballot(v);
        if (lane == w) validw = bal;
    }

    unsigned long long remv = 0, keepw = 0;

    for (int c = 0; c < 16; c++) {
        const unsigned long long* myrow = mrow + (size_t)(c * 64 + lane) * 16;
        unsigned long long m_cc = myrow[c];      // my row, own-word column
        unsigned long long rw[16];
        rw[0] = 0;
        #pragma unroll
        for (int w = 1; w < 16; w++)
            rw[w] = (w > c) ? myrow[w] : 0ULL;

        unsigned long long cur = __shfl(validw & ~remv, c);   // uniform
        for (int jj = 0; jj < 64; jj++) {
            if ((cur >> jj) & 1ULL) {                         // uniform branch
                unsigned long long row = __shfl(m_cc, jj);
                cur &= ~row;                                  // row only has bits > jj
            }
        }
        if (lane == c) keepw = cur;

        bool mykept = ((cur >> lane) & 1ULL) != 0;
        #pragma unroll
        for (int w = 1; w < 16; w++) {
            if (w > c) {
                unsigned long long v = mykept ? rw[w] : 0ULL;
                v |= __shfl_xor(v, 32);
                v |= __shfl_xor(v, 16);
                v |= __shfl_xor(v, 8);
                v |= __shfl_xor(v, 4);
                v |= __shfl_xor(v, 2);
                v |= __shfl_xor(v, 1);
                if (lane == w) remv |= v;
            }
        }
    }

    __shared__ unsigned long long kws[16];
    __shared__ int pfx[17];
    if (lane < 16) kws[lane] = keepw;
    __syncthreads();
    if (lane == 0) {
        int s = 0;
        for (int w = 0; w < 16; w++) { pfx[w] = s; s += __popcll(kws[w]); }
        pfx[16] = s;
    }
    __syncthreads();
    int nk = pfx[16];

    float* ob = out;                       // [8][300][4]
    float* os = out + BB * POST * 4;       // [8][300]
    float* oc = os + BB * POST;            // [8][300]

    for (int r = lane; r < PRE; r += 64) {
        int w = r >> 6;
        unsigned long long kw = kws[w];
        if ((kw >> (r & 63)) & 1ULL) {
            int rank = pfx[w] + __popcll(kw & ((1ULL << (r & 63)) - 1ULL));
            if (rank < POST) {
                ((float4*)ob)[b * POST + rank] = ((const float4*)sboxes)[b * 1024 + r];
                os[b * POST + rank] = sscores[b * 1024 + r];
                oc[b * POST + rank] = scls[b * 1024 + r];
            }
        }
    }
    for (int p = nk + lane; p < POST; p += 64) {
        ((float4*)ob)[b * POST + p] = make_float4(0.f, 0.f, 0.f, 0.f);
        os[b * POST + p] = 0.f;
        oc[b * POST + p] = 0.f;
    }
}

// ---------------- launch ----------------
extern "C" void kernel_launch(void* const* d_in, const int* in_sizes, int n_in,
                              void* d_out, int out_size, void* d_ws, size_t ws_size,
                              hipStream_t stream)
{
    const float* data0 = (const float*)d_in[0];
    const float* data1 = (const float*)d_in[2];
    for (int i = 0; i < n_in; i++) {
        if (in_sizes[i] == 8 * 756 * 6400) data0 = (const float*)d_in[i];
        else if (in_sizes[i] == 8 * 756 * 1600) data1 = (const float*)d_in[i];
    }

    char* ws = (char*)d_ws;
    size_t off = 0;
    auto alloc = [&](size_t bytes) -> char* {
        char* p = ws + off;
        off = (off + bytes + 255) & ~(size_t)255;
        return p;
    };

    float* boxes   = (float*)alloc((size_t)BB * NTOT * 4 * 4);
    float* scores  = (float*)alloc((size_t)BB * NTOT * 4);
    float* cls     = (float*)alloc((size_t)BB * NTOT * 4);
    unsigned* hist = (unsigned*)alloc((size_t)BB * NBINS * 4);
    unsigned* cnt  = (unsigned*)alloc(BB * 4);          // directly after hist (256-aligned)
    unsigned* T    = (unsigned*)alloc(BB * 4);
    unsigned long long* cand = (unsigned long long*)alloc((size_t)BB * CAP * 8);
    float* sboxes  = (float*)alloc((size_t)BB * 1024 * 4 * 4);
    float* sscores = (float*)alloc((size_t)BB * 1024 * 4);
    float* scls    = (float*)alloc((size_t)BB * 1024 * 4);
    unsigned long long* mask = (unsigned long long*)alloc((size_t)BB * 1024 * 16 * 8);

    // zero hist + cnt (contiguous: hist is 2 MB, 256-multiple; cnt follows)
    (void)hipMemsetAsync(hist, 0, (size_t)BB * NBINS * 4 + 256, stream);

    dim3 g0((AA * 1600 + 255) / 256, BB);   // 14400 threads/img
    k_decode<6400, 80, 8, 0><<<g0, 256, 0, stream>>>(data0, boxes, scores, cls, hist);
    dim3 g1((AA * 400 + 255) / 256, BB);    // 3600 threads/img
    k_decode<1600, 40, 16, 57600><<<g1, 256, 0, stream>>>(data1, boxes, scores, cls, hist);

    k_thresh<<<BB, 256, 0, stream>>>(hist, T);

    dim3 g3((NTOT / 4 + 255) / 256, BB);
    k_compact<<<g3, 256, 0, stream>>>(scores, T, cnt, cand);

    k_sort<<<BB, 1024, 0, stream>>>(cand, cnt, boxes, scores, cls, sboxes, sscores, scls);

    dim3 g5(16, BB);
    k_mask<<<g5, 1024, 0, stream>>>(sboxes, sscores, mask);

    k_nms<<<BB, 64, 0, stream>>>(mask, sboxes, sscores, scls, (float*)d_out);
}